// Round 12
// baseline (2996.698 us; speedup 1.0000x reference)
//
#include <hip/hip_runtime.h>

// LSTM_38869454028951: B=512, T=365, F=16, H=256, 2 layers + linear head.
// Round 16: R13 + two counter-backed micro-fixes (protocol identical).
//  1. SIMD rebalance: wave 3's 4th K-slot (L2 Wih2 ks=3) split BY GATE over
//     waves 3-6 (one gate each, +6 MFMA) -> all SIMDs at exactly 150 MFMA
//     (was 144/144/144/168; saves ~465 cy/body tail).
//  2. zb stride 36 -> 38 (16 distinct banks for 16 hcols; was 8) with
//     float4 stores split into 2x float2 (8B-aligned, <=2-way = free).
//  Everything else byte-identical to R13 (K-split waves, packed A LDS,
//  reg x-prefetch, all-512-update 2 cells, padded flags, wave-7 poller
//  + LDS rdy broadcast, lane-contiguous u64 restage).

#define T_STEPS 365
#define RS 564    // A2 row stride in u32
#define ZS 38     // zb column stride in floats (16 distinct banks)

typedef __attribute__((ext_vector_type(8))) short short8;
typedef __attribute__((ext_vector_type(4))) float float4_;
typedef __attribute__((ext_vector_type(2))) float float2_;
typedef __attribute__((ext_vector_type(4))) unsigned int uint4_;
typedef unsigned long long u64;
typedef unsigned int u32;

#define MFMA16(a, b, c) __builtin_amdgcn_mfma_f32_16x16x32_bf16((a), (b), (c), 0, 0, 0)

__device__ __forceinline__ unsigned short f2bf(float v) {
    union { float f; u32 u; } a; a.f = v;
    u32 r = a.u + 0x7fffu + ((a.u >> 16) & 1u);  // RNE
    return (unsigned short)(r >> 16);
}
__device__ __forceinline__ float bf2f(unsigned short h) {
    union { u32 u; float f; } a; a.u = ((u32)h) << 16; return a.f;
}
__device__ __forceinline__ u32 packhl(float v) {
    unsigned short hi = f2bf(v);
    unsigned short lo = f2bf(v - bf2f(hi));
    return ((u32)hi << 16) | (u32)lo;
}
__device__ __forceinline__ float sigm(float x)  { return 1.f / (1.f + __expf(-x)); }
__device__ __forceinline__ float tanh_(float x) { return 2.f / (1.f + __expf(-2.f * x)) - 1.f; }

// unpack 8 packed u32 (hi16|lo16) -> hi short8 + lo short8 (k-order preserved)
__device__ __forceinline__ void unpk(uint4_ a, uint4_ b, short8& hi, short8& lo) {
    union U { u32 d[4]; short8 s; } H, L;
    H.d[0] = __builtin_amdgcn_perm(a.y, a.x, 0x07060302u);
    H.d[1] = __builtin_amdgcn_perm(a.w, a.z, 0x07060302u);
    H.d[2] = __builtin_amdgcn_perm(b.y, b.x, 0x07060302u);
    H.d[3] = __builtin_amdgcn_perm(b.w, b.z, 0x07060302u);
    L.d[0] = __builtin_amdgcn_perm(a.y, a.x, 0x05040100u);
    L.d[1] = __builtin_amdgcn_perm(a.w, a.z, 0x05040100u);
    L.d[2] = __builtin_amdgcn_perm(b.y, b.x, 0x05040100u);
    L.d[3] = __builtin_amdgcn_perm(b.w, b.z, 0x05040100u);
    hi = H.s; lo = L.s;
}

// ---------------- prep: blocked hi/lo weights + biases (UNCHANGED layout) ----------------
// w1blk: [64 tiles][9 ks][16 rows][32 k]; ks<8: Whh1; ks==8: Wih1 (K pad 16->32)
// w2blk: [64][16][16][32]; ks<8: Wih2 (h1 input), ks>=8: Whh2 (h2 input)
__global__ void prep_w(
    const float* __restrict__ Wih1, const float* __restrict__ Whh1,
    const float* __restrict__ bih1, const float* __restrict__ bhh1,
    const float* __restrict__ Wih2, const float* __restrict__ Whh2,
    const float* __restrict__ bih2, const float* __restrict__ bhh2,
    unsigned short* __restrict__ w1h, unsigned short* __restrict__ w1l,
    unsigned short* __restrict__ w2h, unsigned short* __restrict__ w2l,
    float* __restrict__ bias1, float* __restrict__ bias2)
{
    const int tile = blockIdx.x;          // 64
    const int g = tile >> 4, ns = tile & 15;
    const int tid = threadIdx.x;          // 256

    for (int idx = tid; idx < 9 * 512; idx += 256) {
        int ks = idx >> 9, off = idx & 511, r = off >> 5, kk = off & 31;
        int R = g * 256 + ns * 16 + r;
        float v;
        if (ks < 8)       v = Whh1[R * 256 + ks * 32 + kk];
        else if (kk < 16) v = Wih1[R * 16 + kk];
        else              v = 0.f;
        unsigned short h = f2bf(v);
        size_t d = (size_t)(tile * 9 + ks) * 512 + off;
        w1h[d] = h; w1l[d] = f2bf(v - bf2f(h));
    }
    for (int idx = tid; idx < 16 * 512; idx += 256) {
        int ks = idx >> 9, off = idx & 511, r = off >> 5, kk = off & 31;
        int R = g * 256 + ns * 16 + r;
        int k = ks * 32 + kk;
        float v = (k < 256) ? Wih2[R * 256 + k] : Whh2[R * 256 + (k - 256)];
        unsigned short h = f2bf(v);
        size_t d = (size_t)(tile * 16 + ks) * 512 + off;
        w2h[d] = h; w2l[d] = f2bf(v - bf2f(h));
    }
    if (tid < 16) {
        int R = g * 256 + ns * 16 + tid;
        bias1[R] = bih1[R] + bhh1[R];
        bias2[R] = bih2[R] + bhh2[R];
    }
}

// ---------------- main ----------------
__global__ __launch_bounds__(512, 2) void lstm_main(
    const float* __restrict__ x,
    const unsigned short* __restrict__ w1h, const unsigned short* __restrict__ w1l,
    const unsigned short* __restrict__ w2h, const unsigned short* __restrict__ w2l,
    const float* __restrict__ bias1, const float* __restrict__ bias2,
    u32* hb1, u32* hb2, u32* prog,
    const float* __restrict__ Wlin, const float* __restrict__ blin,
    float* __restrict__ out)
{
    __shared__ __align__(16) u32 A2u[32 * RS];            // 70.5 KB packed A
    __shared__ __align__(16) float zb1[3 * 64 * ZS];      // 28.5 KB  L1 partials
    __shared__ __align__(16) float zb2[5 * 64 * ZS];      // 47.5 KB  L2 partials
    __shared__ __align__(16) float hp[32][17];
    __shared__ u32 rdy;                                   // LDS flag broadcast

    const int tid  = threadIdx.x;
    const int lane = tid & 63;
    const int wv   = tid >> 6;            // 8 waves
    const int quad = lane >> 4;
    const int r16  = lane & 15;
    const int bg   = blockIdx.x & 15;     // batch group (peers same XCD)
    const int ns   = blockIdx.x >> 4;     // col slice

    // padded flags: [ns 0..15] x 16 u32 (64B/block); real flags at +wv (0..7)
    u32* myprog = prog + bg * 256;

    // ---- per-wave K-task table (A-block indices; -1 = unused slot) ----
    // L1 (waves 0-2): A-blocks 0..8 (h1 + x), weights w1blk ks = block
    // L2 (waves 3-7): A-blocks {0-2},{4-6},{7,9,10},{11-13},{14-16}; block 3
    //   (Wih2 ks=3) is gate-split across waves 3-6 (one gate each).
    const bool isL1 = (wv < 3);
    int t0, t1_, t2_;
    if      (wv == 0) { t0 = 0;  t1_ = 1;  t2_ = 2;  }
    else if (wv == 1) { t0 = 3;  t1_ = 4;  t2_ = 5;  }
    else if (wv == 2) { t0 = 6;  t1_ = 7;  t2_ = 8;  }
    else if (wv == 3) { t0 = 0;  t1_ = 1;  t2_ = 2;  }
    else if (wv == 4) { t0 = 4;  t1_ = 5;  t2_ = 6;  }
    else if (wv == 5) { t0 = 7;  t1_ = 9;  t2_ = 10; }
    else if (wv == 6) { t0 = 11; t1_ = 12; t2_ = 13; }
    else              { t0 = 14; t1_ = 15; t2_ = 16; }
    const bool hasE = (wv >= 3 && wv <= 6);   // extra: block 3, gate (wv-3)
    const int  egate = wv - 3;

    // ---- preload weights (all 4 gates for this wave's K-blocks) ----
    const int loff = r16 * 32 + quad * 8;
    const unsigned short* WHsrc = isL1 ? w1h : w2h;
    const unsigned short* WLsrc = isL1 ? w1l : w2l;
    const int NK = isL1 ? 9 : 16;
    short8 WH[4][3], WL[4][3];
#pragma unroll
    for (int s = 0; s < 3; s++) {
        const int b = (s == 0) ? t0 : (s == 1) ? t1_ : t2_;
#pragma unroll
        for (int g = 0; g < 4; g++) {
            int ks = (!isL1 && b > 8) ? (b - 1) : b;
            size_t off = ((size_t)((g * 16 + ns) * NK + ks)) * 512 + loff;
            WH[g][s] = *(const short8*)(WHsrc + off);
            WL[g][s] = *(const short8*)(WLsrc + off);
        }
    }
    short8 WHE = short8{0,0,0,0,0,0,0,0}, WLE = WHE;
    if (hasE) {
        size_t off = ((size_t)((egate * 16 + ns) * 16 + 3)) * 512 + loff;  // w2, ks=3
        WHE = *(const short8*)(w2h + off);
        WLE = *(const short8*)(w2l + off);
    }

    // ---- updater state: ALL 512 threads, 2 cells each ----
    const bool is1u = (tid < 256);
    const int hcol = tid & 15;
    const int qrp  = (tid >> 4) & 15;     // row pair index (rows 2q, 2q+1)
    float bi[4];
    {
        const float* bsrc = is1u ? bias1 : bias2;
        int colg = ns * 16 + hcol;
#pragma unroll
        for (int g = 0; g < 4; g++) bi[g] = bsrc[g * 256 + colg];
    }
    float cA = 0.f, cB = 0.f;

    // x mapping: 1 value/thread (row = tid>>4, col = tid&15)
    const int xrow = tid >> 4, xcol = tid & 15;

    // ---- zero A; stage x_0 ----
    for (int i = tid; i < 32 * RS; i += 512) A2u[i] = 0u;
    if (tid == 0) rdy = 0u;
    __syncthreads();
    {
        float v = x[((size_t)(bg * 32 + xrow) * T_STEPS + 0) * 16 + xcol];
        A2u[xrow * RS + 256 + xcol] = packhl(v);
    }
    __syncthreads();

    for (int t = 0; t <= T_STEPS; t++) {   // 366 bodies
        const int p = t & 1;

        // ================= GEMM: per-wave K-slice, 4 gates x 32 rows =================
        float4_ acc[4][2];
        const float4_ z4 = {0.f, 0.f, 0.f, 0.f};
#pragma unroll
        for (int g = 0; g < 4; g++) { acc[g][0] = z4; acc[g][1] = z4; }

        __builtin_amdgcn_s_setprio(1);
#pragma unroll
        for (int s = 0; s < 3; s++) {
            const int b = (s == 0) ? t0 : (s == 1) ? t1_ : t2_;
            {
                const int base0 = r16 * RS + b * 32 + quad * 8;
                uint4_ p00 = *(const uint4_*)&A2u[base0];
                uint4_ p01 = *(const uint4_*)&A2u[base0 + 4];
                uint4_ p10 = *(const uint4_*)&A2u[base0 + 16 * RS];
                uint4_ p11 = *(const uint4_*)&A2u[base0 + 16 * RS + 4];
                short8 ah0, al0, ah1, al1;
                unpk(p00, p01, ah0, al0);
                unpk(p10, p11, ah1, al1);
#pragma unroll
                for (int g = 0; g < 4; g++) {
                    acc[g][0] = MFMA16(ah0, WH[g][s], acc[g][0]);
                    acc[g][0] = MFMA16(al0, WH[g][s], acc[g][0]);
                    acc[g][0] = MFMA16(ah0, WL[g][s], acc[g][0]);
                    acc[g][1] = MFMA16(ah1, WH[g][s], acc[g][1]);
                    acc[g][1] = MFMA16(al1, WH[g][s], acc[g][1]);
                    acc[g][1] = MFMA16(ah1, WL[g][s], acc[g][1]);
                }
            }
        }
        if (hasE) {   // block 3 (h1), gate egate only
            const int base0 = r16 * RS + 3 * 32 + quad * 8;
            uint4_ p00 = *(const uint4_*)&A2u[base0];
            uint4_ p01 = *(const uint4_*)&A2u[base0 + 4];
            uint4_ p10 = *(const uint4_*)&A2u[base0 + 16 * RS];
            uint4_ p11 = *(const uint4_*)&A2u[base0 + 16 * RS + 4];
            short8 ah0, al0, ah1, al1;
            unpk(p00, p01, ah0, al0);
            unpk(p10, p11, ah1, al1);
            acc[egate][0] = MFMA16(ah0, WHE, acc[egate][0]);
            acc[egate][0] = MFMA16(al0, WHE, acc[egate][0]);
            acc[egate][0] = MFMA16(ah0, WLE, acc[egate][0]);
            acc[egate][1] = MFMA16(ah1, WHE, acc[egate][1]);
            acc[egate][1] = MFMA16(al1, WHE, acc[egate][1]);
            acc[egate][1] = MFMA16(ah1, WLE, acc[egate][1]);
        }
        __builtin_amdgcn_s_setprio(0);

        // ---- x_{t+1} prefetch into a register (latency hides under B1) ----
        float xval;
        {
            const int tn = (t + 1 <= T_STEPS - 1) ? (t + 1) : (T_STEPS - 1);
            xval = x[((size_t)(bg * 32 + xrow) * T_STEPS + tn) * 16 + xcol];
        }

        {   // zb partial store: [part][col 0..63][row 0..31 padZS], 2x float2/tile
            float* zbase = isL1 ? (zb1 + wv * (64 * ZS)) : (zb2 + (wv - 3) * (64 * ZS));
#pragma unroll
            for (int g = 0; g < 4; g++)
#pragma unroll
                for (int rt = 0; rt < 2; rt++) {
                    float* dst = &zbase[(size_t)(g * 16 + r16) * ZS + rt * 16 + quad * 4];
                    *(float2_*)dst       = float2_{acc[g][rt].x, acc[g][rt].y};
                    *(float2_*)(dst + 2) = float2_{acc[g][rt].z, acc[g][rt].w};
                }
        }
        __syncthreads();   // B1: zb ready; all A reads done

        // ---- update: ALL threads, 2 cells (rows 2q, 2q+1) of one layer ----
        {
            // x LDS write (A x-window free post-B1; visible at B3)
            A2u[xrow * RS + 256 + xcol] = packhl(xval);

            const float* zb = is1u ? zb1 : zb2;
            const int np = is1u ? 3 : 5;
            float z0[4], z1[4];
#pragma unroll
            for (int g = 0; g < 4; g++) {
                float s0 = bi[g], s1 = bi[g];
#pragma unroll
                for (int pw = 0; pw < 5; pw++) {
                    if (pw < np) {
                        float2_ v = *(const float2_*)&zb[(size_t)(pw * 64 + g * 16 + hcol) * ZS + 2 * qrp];
                        s0 += v.x; s1 += v.y;
                    }
                }
                z0[g] = s0; z1[g] = s1;
            }
            u32* hb = is1u ? hb1 : hb2;
            const int slot = is1u ? p : (1 - p);
            size_t o = (((size_t)slot * 16 + bg) * 32 + 2 * qrp) * 256 + ns * 16 + hcol;
            {
                float nc = sigm(z0[1]) * cA + sigm(z0[0]) * tanh_(z0[2]);
                float h  = sigm(z0[3]) * tanh_(nc);
                if (!is1u && t == 0) { nc = 0.f; h = 0.f; }   // h2_{-1} stays 0
                cA = nc;
                __hip_atomic_store(&hb[o], packhl(h),
                                   __ATOMIC_RELAXED, __HIP_MEMORY_SCOPE_WORKGROUP);
            }
            {
                float nc = sigm(z1[1]) * cB + sigm(z1[0]) * tanh_(z1[2]);
                float h  = sigm(z1[3]) * tanh_(nc);
                if (!is1u && t == 0) { nc = 0.f; h = 0.f; }
                cB = nc;
                __hip_atomic_store(&hb[o + 256], packhl(h),
                                   __ATOMIC_RELAXED, __HIP_MEMORY_SCOPE_WORKGROUP);
            }
            // ---- per-wave drain + padded sub-flag ----
            asm volatile("s_waitcnt vmcnt(0)" ::: "memory");
            if (lane == 0)
                __hip_atomic_store(&myprog[ns * 16 + wv], (u32)(t + 1),
                                   __ATOMIC_RELAXED, __HIP_MEMORY_SCOPE_WORKGROUP);
        }

        if (t == T_STEPS) break;

        // ---- poll: wave 7 watches 128 L2 flags (2/lane), LDS-broadcasts ----
        {
            const u32 tgt = (u32)(t + 1);
            if (wv == 7) {
                const int f1 = (lane >> 2) * 16 + (lane & 3);
                const int f2 = f1 + 4;
                for (;;) {
                    u32 a = __hip_atomic_load(&myprog[f1], __ATOMIC_RELAXED,
                                              __HIP_MEMORY_SCOPE_AGENT);
                    u32 b = __hip_atomic_load(&myprog[f2], __ATOMIC_RELAXED,
                                              __HIP_MEMORY_SCOPE_AGENT);
                    if (a >= tgt && b >= tgt) break;
                    __builtin_amdgcn_s_sleep(1);
                }
                if (lane == 0)
                    __hip_atomic_store(&rdy, tgt, __ATOMIC_RELEASE,
                                       __HIP_MEMORY_SCOPE_WORKGROUP);
            } else {
                while (__hip_atomic_load(&rdy, __ATOMIC_ACQUIRE,
                                         __HIP_MEMORY_SCOPE_WORKGROUP) < tgt) {}
            }
        }

        // ---- restage: wave w copies rows 4w..4w+3 (packed u32, lane-contiguous) ----
        {
            const u64* s1 = (const u64*)(hb1 + (size_t)(p * 16 + bg) * 32 * 256);
            const u64* s2 = (const u64*)(hb2 + (size_t)((1 - p) * 16 + bg) * 32 * 256);
#pragma unroll
            for (int j = 0; j < 4; j++) {
                const int row = wv * 4 + j;
                const u64* r1 = s1 + (size_t)row * 128;
                const u64* r2 = s2 + (size_t)row * 128;
                u64 a = __hip_atomic_load(r1 + lane,      __ATOMIC_RELAXED, __HIP_MEMORY_SCOPE_AGENT);
                u64 b = __hip_atomic_load(r1 + 64 + lane, __ATOMIC_RELAXED, __HIP_MEMORY_SCOPE_AGENT);
                u64 c = __hip_atomic_load(r2 + lane,      __ATOMIC_RELAXED, __HIP_MEMORY_SCOPE_AGENT);
                u64 d = __hip_atomic_load(r2 + 64 + lane, __ATOMIC_RELAXED, __HIP_MEMORY_SCOPE_AGENT);
                u32* dst = &A2u[row * RS];
                *(u64*)&dst[2 * lane]             = a;   // h1 cols 0..127
                *(u64*)&dst[128 + 2 * lane]       = b;   // h1 cols 128..255
                *(u64*)&dst[288 + 2 * lane]       = c;   // h2 cols 0..127
                *(u64*)&dst[288 + 128 + 2 * lane] = d;   // h2 cols 128..255
            }
        }
        __syncthreads();   // B3: A ready for next body (x write + restage drained)
    }

    // ---- head (ns==0): out[b] = h2_364 . Wlin + blin ; hb2 slot 0 ----
    if (ns != 0) return;
    {   // final poll: all 128 real flags at T+1 (2 per lane)
        const u32 tgt = (u32)(T_STEPS + 1);
        const int f1 = (lane >> 2) * 16 + (lane & 3);
        const int f2 = f1 + 4;
        for (;;) {
            u32 a = __hip_atomic_load(&myprog[f1], __ATOMIC_RELAXED,
                                      __HIP_MEMORY_SCOPE_AGENT);
            u32 b = __hip_atomic_load(&myprog[f2], __ATOMIC_RELAXED,
                                      __HIP_MEMORY_SCOPE_AGENT);
            if (a >= tgt && b >= tgt) break;
            __builtin_amdgcn_s_sleep(1);
        }
    }
    {
        int row = tid >> 4, seg = tid & 15;
        const u32* src = hb2 + ((size_t)bg * 32 + row) * 256 + seg * 16;   // slot 0
        float s = 0.f;
#pragma unroll
        for (int j = 0; j < 16; j++) {
            u32 v = __hip_atomic_load(&src[j], __ATOMIC_RELAXED, __HIP_MEMORY_SCOPE_AGENT);
            s += (bf2f((unsigned short)(v >> 16)) + bf2f((unsigned short)v)) * Wlin[seg * 16 + j];
        }
        hp[row][seg] = s;
    }
    __syncthreads();
    if (tid < 32) {
        float s = 0.f;
#pragma unroll
        for (int j = 0; j < 16; j++) s += hp[tid][j];
        out[bg * 32 + tid] = s + blin[0];
    }
}

extern "C" void kernel_launch(void* const* d_in, const int* in_sizes, int n_in,
                              void* d_out, int out_size, void* d_ws, size_t ws_size,
                              hipStream_t stream) {
    const float* x    = (const float*)d_in[0];
    const float* Wih1 = (const float*)d_in[1];
    const float* Whh1 = (const float*)d_in[2];
    const float* bih1 = (const float*)d_in[3];
    const float* bhh1 = (const float*)d_in[4];
    const float* Wih2 = (const float*)d_in[5];
    const float* Whh2 = (const float*)d_in[6];
    const float* bih2 = (const float*)d_in[7];
    const float* bhh2 = (const float*)d_in[8];
    const float* Wlin = (const float*)d_in[9];
    const float* blin = (const float*)d_in[10];
    float* out = (float*)d_out;

    char* pp = (char*)d_ws;
    unsigned short* w1h = (unsigned short*)pp; pp += (size_t)64 * 9 * 512 * 2;
    unsigned short* w1l = (unsigned short*)pp; pp += (size_t)64 * 9 * 512 * 2;
    unsigned short* w2h = (unsigned short*)pp; pp += (size_t)64 * 16 * 512 * 2;
    unsigned short* w2l = (unsigned short*)pp; pp += (size_t)64 * 16 * 512 * 2;
    float* bias1 = (float*)pp; pp += 1024 * 4;
    float* bias2 = (float*)pp; pp += 1024 * 4;
    char* zero_base = pp;
    u32* hb1 = (u32*)pp; pp += (size_t)2 * 16 * 32 * 256 * 4;   // 1 MB
    u32* hb2 = (u32*)pp; pp += (size_t)2 * 16 * 32 * 256 * 4;   // 1 MB
    u32* prog = (u32*)pp; pp += 16 * 256 * 4;                    // padded flags
    size_t zero_bytes = (size_t)(pp - zero_base);

    hipMemsetAsync(zero_base, 0, zero_bytes, stream);
    prep_w<<<64, 256, 0, stream>>>(Wih1, Whh1, bih1, bhh1, Wih2, Whh2, bih2, bhh2,
                                   w1h, w1l, w2h, w2l, bias1, bias2);
    lstm_main<<<256, 512, 0, stream>>>(x, w1h, w1l, w2h, w2l, bias1, bias2,
                                       hb1, hb2, prog, Wlin, blin, out);
}

// Round 13
// 1633.696 us; speedup vs baseline: 1.8343x; 1.8343x over previous
//
#include <hip/hip_runtime.h>

// LSTM_38869454028951: B=512, T=365, F=16, H=256, 2 layers + linear head.
// Round 17: REVERT to R13 (best measured: 1634 us). R16's micro-fixes
// (zb restride 38 + float2 stores, gate-split rebalance) regressed 83% —
// broken b128 coalescing + serial acc chains. R13 byte-identical:
//  - K-split wave specialization (L1 waves 0-2, L2 waves 3-7), weights in regs.
//  - Packed A (bf16 hi|lo u32) in LDS; lane-contiguous u64 restage from L2.
//  - Update spread over ALL 512 threads (2 cells each); reg x-prefetch.
//  - Padded per-wave flags; wave-7 poller + LDS rdy broadcast; workgroup-
//    scope publishes (L2-visible), agent-scope consumes.

#define T_STEPS 365
#define RS 564   // A2 row stride in u32; row: [0..255]=h1 [256..287]=x+pad [288..543]=h2 [544..563]=pad

typedef __attribute__((ext_vector_type(8))) short short8;
typedef __attribute__((ext_vector_type(4))) float float4_;
typedef __attribute__((ext_vector_type(2))) float float2_;
typedef __attribute__((ext_vector_type(4))) unsigned int uint4_;
typedef unsigned long long u64;
typedef unsigned int u32;

#define MFMA16(a, b, c) __builtin_amdgcn_mfma_f32_16x16x32_bf16((a), (b), (c), 0, 0, 0)

__device__ __forceinline__ unsigned short f2bf(float v) {
    union { float f; u32 u; } a; a.f = v;
    u32 r = a.u + 0x7fffu + ((a.u >> 16) & 1u);  // RNE
    return (unsigned short)(r >> 16);
}
__device__ __forceinline__ float bf2f(unsigned short h) {
    union { u32 u; float f; } a; a.u = ((u32)h) << 16; return a.f;
}
__device__ __forceinline__ u32 packhl(float v) {
    unsigned short hi = f2bf(v);
    unsigned short lo = f2bf(v - bf2f(hi));
    return ((u32)hi << 16) | (u32)lo;
}
__device__ __forceinline__ float sigm(float x)  { return 1.f / (1.f + __expf(-x)); }
__device__ __forceinline__ float tanh_(float x) { return 2.f / (1.f + __expf(-2.f * x)) - 1.f; }

// unpack 8 packed u32 (hi16|lo16) -> hi short8 + lo short8 (k-order preserved)
__device__ __forceinline__ void unpk(uint4_ a, uint4_ b, short8& hi, short8& lo) {
    union U { u32 d[4]; short8 s; } H, L;
    H.d[0] = __builtin_amdgcn_perm(a.y, a.x, 0x07060302u);
    H.d[1] = __builtin_amdgcn_perm(a.w, a.z, 0x07060302u);
    H.d[2] = __builtin_amdgcn_perm(b.y, b.x, 0x07060302u);
    H.d[3] = __builtin_amdgcn_perm(b.w, b.z, 0x07060302u);
    L.d[0] = __builtin_amdgcn_perm(a.y, a.x, 0x05040100u);
    L.d[1] = __builtin_amdgcn_perm(a.w, a.z, 0x05040100u);
    L.d[2] = __builtin_amdgcn_perm(b.y, b.x, 0x05040100u);
    L.d[3] = __builtin_amdgcn_perm(b.w, b.z, 0x05040100u);
    hi = H.s; lo = L.s;
}

// ---------------- prep: blocked hi/lo weights + biases (UNCHANGED layout) ----------------
// w1blk: [64 tiles][9 ks][16 rows][32 k]; ks<8: Whh1; ks==8: Wih1 (K pad 16->32)
// w2blk: [64][16][16][32]; ks<8: Wih2 (h1 input), ks>=8: Whh2 (h2 input)
__global__ void prep_w(
    const float* __restrict__ Wih1, const float* __restrict__ Whh1,
    const float* __restrict__ bih1, const float* __restrict__ bhh1,
    const float* __restrict__ Wih2, const float* __restrict__ Whh2,
    const float* __restrict__ bih2, const float* __restrict__ bhh2,
    unsigned short* __restrict__ w1h, unsigned short* __restrict__ w1l,
    unsigned short* __restrict__ w2h, unsigned short* __restrict__ w2l,
    float* __restrict__ bias1, float* __restrict__ bias2)
{
    const int tile = blockIdx.x;          // 64
    const int g = tile >> 4, ns = tile & 15;
    const int tid = threadIdx.x;          // 256

    for (int idx = tid; idx < 9 * 512; idx += 256) {
        int ks = idx >> 9, off = idx & 511, r = off >> 5, kk = off & 31;
        int R = g * 256 + ns * 16 + r;
        float v;
        if (ks < 8)       v = Whh1[R * 256 + ks * 32 + kk];
        else if (kk < 16) v = Wih1[R * 16 + kk];
        else              v = 0.f;
        unsigned short h = f2bf(v);
        size_t d = (size_t)(tile * 9 + ks) * 512 + off;
        w1h[d] = h; w1l[d] = f2bf(v - bf2f(h));
    }
    for (int idx = tid; idx < 16 * 512; idx += 256) {
        int ks = idx >> 9, off = idx & 511, r = off >> 5, kk = off & 31;
        int R = g * 256 + ns * 16 + r;
        int k = ks * 32 + kk;
        float v = (k < 256) ? Wih2[R * 256 + k] : Whh2[R * 256 + (k - 256)];
        unsigned short h = f2bf(v);
        size_t d = (size_t)(tile * 16 + ks) * 512 + off;
        w2h[d] = h; w2l[d] = f2bf(v - bf2f(h));
    }
    if (tid < 16) {
        int R = g * 256 + ns * 16 + tid;
        bias1[R] = bih1[R] + bhh1[R];
        bias2[R] = bih2[R] + bhh2[R];
    }
}

// ---------------- main ----------------
__global__ __launch_bounds__(512, 2) void lstm_main(
    const float* __restrict__ x,
    const unsigned short* __restrict__ w1h, const unsigned short* __restrict__ w1l,
    const unsigned short* __restrict__ w2h, const unsigned short* __restrict__ w2l,
    const float* __restrict__ bias1, const float* __restrict__ bias2,
    u32* hb1, u32* hb2, u32* prog,
    const float* __restrict__ Wlin, const float* __restrict__ blin,
    float* __restrict__ out)
{
    __shared__ __align__(16) u32 A2u[32 * RS];            // 70.5 KB packed A
    __shared__ __align__(16) float zb1[3 * 64 * 36];      // 27 KB  L1 partials
    __shared__ __align__(16) float zb2[5 * 64 * 36];      // 45 KB  L2 partials
    __shared__ __align__(16) float hp[32][17];
    __shared__ u32 rdy;                                   // LDS flag broadcast

    const int tid  = threadIdx.x;
    const int lane = tid & 63;
    const int wv   = tid >> 6;            // 8 waves
    const int quad = lane >> 4;
    const int r16  = lane & 15;
    const int bg   = blockIdx.x & 15;     // batch group (peers same XCD)
    const int ns   = blockIdx.x >> 4;     // col slice

    // padded flags: [ns 0..15] x 16 u32 (64B/block); real flags at +wv (0..7)
    u32* myprog = prog + bg * 256;

    // ---- per-wave K-task table (A-block indices; -1 = unused slot) ----
    // L1 (waves 0-2): A-blocks 0..8 (h1 + x), weights w1blk ks = block
    // L2 (waves 3-7): A-blocks 0..7 (h1/Wih2) and 9..16 (h2/Whh2), ks = b<8?b:b-1
    const bool isL1 = (wv < 3);
    int t0, t1_, t2_, t3_;
    if      (wv == 0) { t0 = 0;  t1_ = 1;  t2_ = 2;  t3_ = -1; }
    else if (wv == 1) { t0 = 3;  t1_ = 4;  t2_ = 5;  t3_ = -1; }
    else if (wv == 2) { t0 = 6;  t1_ = 7;  t2_ = 8;  t3_ = -1; }
    else if (wv == 3) { t0 = 0;  t1_ = 1;  t2_ = 2;  t3_ = 3;  }
    else if (wv == 4) { t0 = 4;  t1_ = 5;  t2_ = 6;  t3_ = -1; }
    else if (wv == 5) { t0 = 7;  t1_ = 9;  t2_ = 10; t3_ = -1; }
    else if (wv == 6) { t0 = 11; t1_ = 12; t2_ = 13; t3_ = -1; }
    else              { t0 = 14; t1_ = 15; t2_ = 16; t3_ = -1; }

    // ---- preload weights (all 4 gates for this wave's K-blocks) ----
    const int loff = r16 * 32 + quad * 8;
    const unsigned short* WHsrc = isL1 ? w1h : w2h;
    const unsigned short* WLsrc = isL1 ? w1l : w2l;
    const int NK = isL1 ? 9 : 16;
    short8 WH[4][4], WL[4][4];
#pragma unroll
    for (int s = 0; s < 4; s++) {
        const int b = (s == 0) ? t0 : (s == 1) ? t1_ : (s == 2) ? t2_ : t3_;
#pragma unroll
        for (int g = 0; g < 4; g++) {
            if (b >= 0) {
                int ks = (!isL1 && b > 8) ? (b - 1) : b;
                size_t off = ((size_t)((g * 16 + ns) * NK + ks)) * 512 + loff;
                WH[g][s] = *(const short8*)(WHsrc + off);
                WL[g][s] = *(const short8*)(WLsrc + off);
            } else {
                WH[g][s] = short8{0,0,0,0,0,0,0,0};
                WL[g][s] = short8{0,0,0,0,0,0,0,0};
            }
        }
    }

    // ---- updater state: ALL 512 threads, 2 cells each ----
    const bool is1u = (tid < 256);
    const int hcol = tid & 15;
    const int qrp  = (tid >> 4) & 15;     // row pair index
    float bi[4];
    {
        const float* bsrc = is1u ? bias1 : bias2;
        int colg = ns * 16 + hcol;
#pragma unroll
        for (int g = 0; g < 4; g++) bi[g] = bsrc[g * 256 + colg];
    }
    float cA = 0.f, cB = 0.f;

    // x mapping: 1 value/thread (row = tid>>4, col = tid&15)
    const int xrow = tid >> 4, xcol = tid & 15;

    // ---- zero A; stage x_0 ----
    for (int i = tid; i < 32 * RS; i += 512) A2u[i] = 0u;
    if (tid == 0) rdy = 0u;
    __syncthreads();
    {
        float v = x[((size_t)(bg * 32 + xrow) * T_STEPS + 0) * 16 + xcol];
        A2u[xrow * RS + 256 + xcol] = packhl(v);
    }
    __syncthreads();

    for (int t = 0; t <= T_STEPS; t++) {   // 366 bodies
        const int p = t & 1;

        // ================= GEMM: per-wave K-slice, 4 gates x 32 rows =================
        float4_ acc[4][2];
        const float4_ z4 = {0.f, 0.f, 0.f, 0.f};
#pragma unroll
        for (int g = 0; g < 4; g++) { acc[g][0] = z4; acc[g][1] = z4; }

        __builtin_amdgcn_s_setprio(1);
#pragma unroll
        for (int s = 0; s < 4; s++) {
            const int b = (s == 0) ? t0 : (s == 1) ? t1_ : (s == 2) ? t2_ : t3_;
            if (b >= 0) {
                const int base0 = r16 * RS + b * 32 + quad * 8;
                uint4_ p00 = *(const uint4_*)&A2u[base0];
                uint4_ p01 = *(const uint4_*)&A2u[base0 + 4];
                uint4_ p10 = *(const uint4_*)&A2u[base0 + 16 * RS];
                uint4_ p11 = *(const uint4_*)&A2u[base0 + 16 * RS + 4];
                short8 ah0, al0, ah1, al1;
                unpk(p00, p01, ah0, al0);
                unpk(p10, p11, ah1, al1);
#pragma unroll
                for (int g = 0; g < 4; g++) {
                    acc[g][0] = MFMA16(ah0, WH[g][s], acc[g][0]);
                    acc[g][0] = MFMA16(al0, WH[g][s], acc[g][0]);
                    acc[g][0] = MFMA16(ah0, WL[g][s], acc[g][0]);
                    acc[g][1] = MFMA16(ah1, WH[g][s], acc[g][1]);
                    acc[g][1] = MFMA16(al1, WH[g][s], acc[g][1]);
                    acc[g][1] = MFMA16(ah1, WL[g][s], acc[g][1]);
                }
            }
        }
        __builtin_amdgcn_s_setprio(0);

        // ---- x_{t+1} prefetch into a register (latency hides under B1) ----
        float xval;
        {
            const int tn = (t + 1 <= T_STEPS - 1) ? (t + 1) : (T_STEPS - 1);
            xval = x[((size_t)(bg * 32 + xrow) * T_STEPS + tn) * 16 + xcol];
        }

        {   // zb partial store: [part][col 0..63][row 0..31 pad36], float4 per tile
            float* zbase = isL1 ? (zb1 + wv * (64 * 36)) : (zb2 + (wv - 3) * (64 * 36));
#pragma unroll
            for (int g = 0; g < 4; g++)
#pragma unroll
                for (int rt = 0; rt < 2; rt++)
                    *(float4_*)&zbase[(size_t)(g * 16 + r16) * 36 + rt * 16 + quad * 4] = acc[g][rt];
        }
        __syncthreads();   // B1: zb ready; all A reads done

        // ---- update: ALL threads, 2 cells (rows 2q, 2q+1) of one layer ----
        {
            // x LDS write (A x-window free post-B1; visible at B3)
            A2u[xrow * RS + 256 + xcol] = packhl(xval);

            const float* zb = is1u ? zb1 : zb2;
            const int np = is1u ? 3 : 5;
            float z0[4], z1[4];
#pragma unroll
            for (int g = 0; g < 4; g++) {
                float s0 = bi[g], s1 = bi[g];
#pragma unroll
                for (int pw = 0; pw < 5; pw++) {
                    if (pw < np) {
                        float2_ v = *(const float2_*)&zb[(size_t)(pw * 64 + g * 16 + hcol) * 36 + 2 * qrp];
                        s0 += v.x; s1 += v.y;
                    }
                }
                z0[g] = s0; z1[g] = s1;
            }
            u32* hb = is1u ? hb1 : hb2;
            const int slot = is1u ? p : (1 - p);
            size_t o = (((size_t)slot * 16 + bg) * 32 + 2 * qrp) * 256 + ns * 16 + hcol;
            {
                float nc = sigm(z0[1]) * cA + sigm(z0[0]) * tanh_(z0[2]);
                float h  = sigm(z0[3]) * tanh_(nc);
                if (!is1u && t == 0) { nc = 0.f; h = 0.f; }   // h2_{-1} stays 0
                cA = nc;
                __hip_atomic_store(&hb[o], packhl(h),
                                   __ATOMIC_RELAXED, __HIP_MEMORY_SCOPE_WORKGROUP);
            }
            {
                float nc = sigm(z1[1]) * cB + sigm(z1[0]) * tanh_(z1[2]);
                float h  = sigm(z1[3]) * tanh_(nc);
                if (!is1u && t == 0) { nc = 0.f; h = 0.f; }
                cB = nc;
                __hip_atomic_store(&hb[o + 256], packhl(h),
                                   __ATOMIC_RELAXED, __HIP_MEMORY_SCOPE_WORKGROUP);
            }
            // ---- per-wave drain + padded sub-flag ----
            asm volatile("s_waitcnt vmcnt(0)" ::: "memory");
            if (lane == 0)
                __hip_atomic_store(&myprog[ns * 16 + wv], (u32)(t + 1),
                                   __ATOMIC_RELAXED, __HIP_MEMORY_SCOPE_WORKGROUP);
        }

        if (t == T_STEPS) break;

        // ---- poll: wave 7 watches 128 L2 flags (2/lane), LDS-broadcasts ----
        {
            const u32 tgt = (u32)(t + 1);
            if (wv == 7) {
                const int f1 = (lane >> 2) * 16 + (lane & 3);
                const int f2 = f1 + 4;
                for (;;) {
                    u32 a = __hip_atomic_load(&myprog[f1], __ATOMIC_RELAXED,
                                              __HIP_MEMORY_SCOPE_AGENT);
                    u32 b = __hip_atomic_load(&myprog[f2], __ATOMIC_RELAXED,
                                              __HIP_MEMORY_SCOPE_AGENT);
                    if (a >= tgt && b >= tgt) break;
                    __builtin_amdgcn_s_sleep(1);
                }
                if (lane == 0)
                    __hip_atomic_store(&rdy, tgt, __ATOMIC_RELEASE,
                                       __HIP_MEMORY_SCOPE_WORKGROUP);
            } else {
                while (__hip_atomic_load(&rdy, __ATOMIC_ACQUIRE,
                                         __HIP_MEMORY_SCOPE_WORKGROUP) < tgt) {}
            }
        }

        // ---- restage: wave w copies rows 4w..4w+3 (packed u32, lane-contiguous) ----
        {
            const u64* s1 = (const u64*)(hb1 + (size_t)(p * 16 + bg) * 32 * 256);
            const u64* s2 = (const u64*)(hb2 + (size_t)((1 - p) * 16 + bg) * 32 * 256);
#pragma unroll
            for (int j = 0; j < 4; j++) {
                const int row = wv * 4 + j;
                const u64* r1 = s1 + (size_t)row * 128;
                const u64* r2 = s2 + (size_t)row * 128;
                u64 a = __hip_atomic_load(r1 + lane,      __ATOMIC_RELAXED, __HIP_MEMORY_SCOPE_AGENT);
                u64 b = __hip_atomic_load(r1 + 64 + lane, __ATOMIC_RELAXED, __HIP_MEMORY_SCOPE_AGENT);
                u64 c = __hip_atomic_load(r2 + lane,      __ATOMIC_RELAXED, __HIP_MEMORY_SCOPE_AGENT);
                u64 d = __hip_atomic_load(r2 + 64 + lane, __ATOMIC_RELAXED, __HIP_MEMORY_SCOPE_AGENT);
                u32* dst = &A2u[row * RS];
                *(u64*)&dst[2 * lane]             = a;   // h1 cols 0..127
                *(u64*)&dst[128 + 2 * lane]       = b;   // h1 cols 128..255
                *(u64*)&dst[288 + 2 * lane]       = c;   // h2 cols 0..127
                *(u64*)&dst[288 + 128 + 2 * lane] = d;   // h2 cols 128..255
            }
        }
        __syncthreads();   // B3: A ready for next body (x write + restage drained)
    }

    // ---- head (ns==0): out[b] = h2_364 . Wlin + blin ; hb2 slot 0 ----
    if (ns != 0) return;
    {   // final poll: all 128 real flags at T+1 (2 per lane)
        const u32 tgt = (u32)(T_STEPS + 1);
        const int f1 = (lane >> 2) * 16 + (lane & 3);
        const int f2 = f1 + 4;
        for (;;) {
            u32 a = __hip_atomic_load(&myprog[f1], __ATOMIC_RELAXED,
                                      __HIP_MEMORY_SCOPE_AGENT);
            u32 b = __hip_atomic_load(&myprog[f2], __ATOMIC_RELAXED,
                                      __HIP_MEMORY_SCOPE_AGENT);
            if (a >= tgt && b >= tgt) break;
            __builtin_amdgcn_s_sleep(1);
        }
    }
    {
        int row = tid >> 4, seg = tid & 15;
        const u32* src = hb2 + ((size_t)bg * 32 + row) * 256 + seg * 16;   // slot 0
        float s = 0.f;
#pragma unroll
        for (int j = 0; j < 16; j++) {
            u32 v = __hip_atomic_load(&src[j], __ATOMIC_RELAXED, __HIP_MEMORY_SCOPE_AGENT);
            s += (bf2f((unsigned short)(v >> 16)) + bf2f((unsigned short)v)) * Wlin[seg * 16 + j];
        }
        hp[row][seg] = s;
    }
    __syncthreads();
    if (tid < 32) {
        float s = 0.f;
#pragma unroll
        for (int j = 0; j < 16; j++) s += hp[tid][j];
        out[bg * 32 + tid] = s + blin[0];
    }
}

extern "C" void kernel_launch(void* const* d_in, const int* in_sizes, int n_in,
                              void* d_out, int out_size, void* d_ws, size_t ws_size,
                              hipStream_t stream) {
    const float* x    = (const float*)d_in[0];
    const float* Wih1 = (const float*)d_in[1];
    const float* Whh1 = (const float*)d_in[2];
    const float* bih1 = (const float*)d_in[3];
    const float* bhh1 = (const float*)d_in[4];
    const float* Wih2 = (const float*)d_in[5];
    const float* Whh2 = (const float*)d_in[6];
    const float* bih2 = (const float*)d_in[7];
    const float* bhh2 = (const float*)d_in[8];
    const float* Wlin = (const float*)d_in[9];
    const float* blin = (const float*)d_in[10];
    float* out = (float*)d_out;

    char* pp = (char*)d_ws;
    unsigned short* w1h = (unsigned short*)pp; pp += (size_t)64 * 9 * 512 * 2;
    unsigned short* w1l = (unsigned short*)pp; pp += (size_t)64 * 9 * 512 * 2;
    unsigned short* w2h = (unsigned short*)pp; pp += (size_t)64 * 16 * 512 * 2;
    unsigned short* w2l = (unsigned short*)pp; pp += (size_t)64 * 16 * 512 * 2;
    float* bias1 = (float*)pp; pp += 1024 * 4;
    float* bias2 = (float*)pp; pp += 1024 * 4;
    char* zero_base = pp;
    u32* hb1 = (u32*)pp; pp += (size_t)2 * 16 * 32 * 256 * 4;   // 1 MB
    u32* hb2 = (u32*)pp; pp += (size_t)2 * 16 * 32 * 256 * 4;   // 1 MB
    u32* prog = (u32*)pp; pp += 16 * 256 * 4;                    // padded flags
    size_t zero_bytes = (size_t)(pp - zero_base);

    hipMemsetAsync(zero_base, 0, zero_bytes, stream);
    prep_w<<<64, 256, 0, stream>>>(Wih1, Whh1, bih1, bhh1, Wih2, Whh2, bih2, bhh2,
                                   w1h, w1l, w2h, w2l, bias1, bias2);
    lstm_main<<<256, 512, 0, stream>>>(x, w1h, w1l, w2h, w2l, bias1, bias2,
                                       hb1, hb2, prog, Wlin, blin, out);
}